// Round 10
// baseline (318.535 us; speedup 1.0000x reference)
//
#include <hip/hip_runtime.h>
#include <hip/hip_bf16.h>

typedef short s16x8 __attribute__((ext_vector_type(8)));
typedef float f32x4 __attribute__((ext_vector_type(4)));

namespace {
constexpr int kB   = 8;
constexpr int kN   = 5000;
constexpr int kE   = 40000;
constexpr int kF   = 64;
constexpr int kFE  = 16;
constexpr int kFil = 96;
constexpr float kEps = 1e-3f;
constexpr int kBN = kB * kN;   // 40000
constexpr int kBE = kB * kE;   // 320000
constexpr int kKp = 160;       // padded K (msg 144->160, upd exact 160)
constexpr int kLd = 168;       // LDS row stride in bf16 elems (r3-proven)
constexpr int kBM = 128;       // rows per block (upd: 4 waves x 2 tiles)
constexpr int kBM2 = 256;      // rows per block (msg: 8 waves x 2 tiles)
constexpr int kZChunks = kBN * kFil / 8;          // 480000 16B agg chunks
constexpr int kZPerBlk = kZChunks / (kBE / kBM2); // 384 per msg block
}

// float -> bf16 (RNE) bit-twiddle — kept only for the tiny prep kernel
__device__ inline unsigned short f2bf(float x) {
    unsigned u = __float_as_uint(x);
    u += 0x7FFFu + ((u >> 16) & 1u);
    return (unsigned short)(u >> 16);
}

// 8x fp32 -> 8x bf16 via v_cvt_pk_bf16_f32 (RNE)
__device__ inline s16x8 pack8(const float4& a, const float4& b) {
    union { s16x8 s; __hip_bfloat162 h[4]; } r;
    r.h[0] = __float22bfloat162_rn(make_float2(a.x, a.y));
    r.h[1] = __float22bfloat162_rn(make_float2(a.z, a.w));
    r.h[2] = __float22bfloat162_rn(make_float2(b.x, b.y));
    r.h[3] = __float22bfloat162_rn(make_float2(b.z, b.w));
    return r.s;
}

// Load 8 consecutive fp32 (16B-aligned) -> bf16x8 A-fragment
__device__ inline s16x8 loadA8(const float* __restrict__ p) {
    const float4* q = reinterpret_cast<const float4*>(p);
    return pack8(q[0], q[1]);
}

// ---------------------------------------------------------------------------
// DPP cross-lane helpers (16-lane-row scope) — 1 VALU op per exchange,
// zero LDS traffic (r9-proven). quad_perm 0xB1 (xor1), 0x4E (xor2),
// row_ror:4 = 0x124, row_ror:8 = 0x128.
// ---------------------------------------------------------------------------
template <int CTRL>
__device__ inline float dpp_mov(float x) {
    return __int_as_float(__builtin_amdgcn_update_dpp(
        0, __float_as_int(x), CTRL, 0xF, 0xF, true));
}
__device__ inline float row16_sum(float s) {
    s += dpp_mov<0xB1>(s);    // + xor1
    s += dpp_mov<0x4E>(s);    // + xor2  -> quad sums
    s += dpp_mov<0x124>(s);   // + ror4
    s += dpp_mov<0x128>(s);   // + ror8  -> full 16-lane sum in every lane
    return s;
}

// ---------------------------------------------------------------------------
// Prep: W (K,96) fp32 -> WT (96,Kp) bf16, zero-padded K rows. 60 blocks.
// ---------------------------------------------------------------------------
__global__ __launch_bounds__(256) void prep_wT(
    const float* __restrict__ Wm, const float* __restrict__ Wu,
    short* __restrict__ wmT, short* __restrict__ wuT) {
    const int t = blockIdx.x * 256 + threadIdx.x;
    if (t >= 96 * kKp) return;
    const int n = t / kKp, k = t % kKp;
    wmT[t] = (k < 144) ? (short)f2bf(Wm[(size_t)k * 96 + n]) : (short)0;
    wuT[t] = (short)f2bf(Wu[(size_t)k * 96 + n]);
}

// ---------------------------------------------------------------------------
// bias/ReLU/LN epilogue + paired float2 store for one 16-row output tile
// group. acc layout: col=16t+cl, row=row0+j. All cross-lane via DPP.
// ---------------------------------------------------------------------------
__device__ inline void ln_epilogue(const f32x4 acc[6],
                                   const float bmv[6], const float gv[6],
                                   const float bv[6],
                                   float* __restrict__ out,
                                   int row0, int cl, int rowMax) {
#pragma unroll
    for (int j = 0; j < 4; ++j) {
        float v0[6];
        float s = 0.f;
#pragma unroll
        for (int t = 0; t < 6; ++t) {
            v0[t] = fmaxf(acc[t][j] + bmv[t], 0.f);
            s += v0[t];
        }
        s = row16_sum(s);
        const float mu = s * (1.f / 96.f);
        float q = 0.f;
#pragma unroll
        for (int t = 0; t < 6; ++t) {
            const float d = v0[t] - mu;
            q = fmaf(d, d, q);
        }
        q = row16_sum(q);
        const float inv = rsqrtf(q * (1.f / 96.f) + kEps);
        const int row = row0 + j;
        if (row < rowMax) {
            float* orow = out + (size_t)row * kFil;
            float ov[6];
#pragma unroll
            for (int t = 0; t < 6; ++t)
                ov[t] = (v0[t] - mu) * inv * gv[t] + bv[t];
#pragma unroll
            for (int t = 0; t < 6; ++t) {
                const float other = dpp_mov<0xB1>(ov[t]);   // partner col (xor1)
                if ((cl & 1) == 0) {
                    float2 st; st.x = ov[t]; st.y = other;
                    *reinterpret_cast<float2*>(orow + 16 * t + cl) = st;
                }
            }
        }
    }
}

// ---------------------------------------------------------------------------
// Message layer (MFMA): block = 256 edges, 8 waves; each wave owns TWO
// 16-row tiles (rA0, rA0+128) sharing every B-fragment ds_read. A-fragments
// loaded directly from global. Also zeroes its 6 KB agg slice (ordered
// before scatter by the kernel boundary; overlaps gather latency).
// ---------------------------------------------------------------------------
__global__ __launch_bounds__(512) void msg_gemm(
    const float* __restrict__ nodes, const float* __restrict__ efeat,
    const int* __restrict__ edges, const short* __restrict__ wmT,
    const float* __restrict__ bm, const float* __restrict__ g,
    const float* __restrict__ be, float* __restrict__ out_msg,
    s16x8* __restrict__ aggz) {
    __shared__ short sB[96 * kLd];    // 32256 B
    const int tid  = threadIdx.x;
    const int w    = tid >> 6;
    const int lane = tid & 63;
    const int cl   = lane & 15;
    const int quad = lane >> 4;

    const int rA0 = blockIdx.x * kBM2 + 16 * w + cl;   // 1250*256 = 320000 exact
    const int rA1 = rA0 + 128;
    const int b0  = rA0 / kE;
    const int b1  = rA1 / kE;
    const int2 e0 = reinterpret_cast<const int2*>(edges)[rA0];
    const int2 e1 = reinterpret_cast<const int2*>(edges)[rA1];
    const float* s0p = nodes + ((size_t)b0 * kN + e0.x) * kF + 8 * quad;
    const float* d0p = nodes + ((size_t)b0 * kN + e0.y) * kF + 8 * quad;
    const float* s1p = nodes + ((size_t)b1 * kN + e1.x) * kF + 8 * quad;
    const float* d1p = nodes + ((size_t)b1 * kN + e1.y) * kF + 8 * quad;

    s16x8 a0[5], a1[5];
    a0[0] = loadA8(s0p);       a1[0] = loadA8(s1p);
    a0[1] = loadA8(s0p + 32);  a1[1] = loadA8(s1p + 32);
    a0[2] = loadA8(d0p);       a1[2] = loadA8(d1p);
    a0[3] = loadA8(d0p + 32);  a1[3] = loadA8(d1p + 32);
    if (quad < 2) {
        a0[4] = loadA8(efeat + (size_t)rA0 * kFE + 8 * quad);
        a1[4] = loadA8(efeat + (size_t)rA1 * kFE + 8 * quad);
    } else {
        s16x8 z = {};
        a0[4] = z; a1[4] = z;          // zero-pad K 144..159
    }

    // zero this block's agg slice (384 16B chunks; threads 0..383)
    if (tid < kZPerBlk) {
        s16x8 z = {};
        aggz[(size_t)blockIdx.x * kZPerBlk + tid] = z;
    }

    for (int i = tid; i < 96 * kKp / 8; i += 512) {   // 1920 16B chunks
        const int n = i / 20, c = i % 20;
        *reinterpret_cast<s16x8*>(sB + n * kLd + 8 * c) =
            *reinterpret_cast<const s16x8*>(wmT + n * kKp + 8 * c);
    }
    __syncthreads();

    f32x4 acc0[6] = {}, acc1[6] = {};
#pragma unroll
    for (int ks = 0; ks < 5; ++ks) {
#pragma unroll
        for (int t = 0; t < 6; ++t) {
            s16x8 bfr = *reinterpret_cast<const s16x8*>(
                sB + (16 * t + cl) * kLd + ks * 32 + quad * 8);
            acc0[t] = __builtin_amdgcn_mfma_f32_16x16x32_bf16(a0[ks], bfr, acc0[t], 0, 0, 0);
            acc1[t] = __builtin_amdgcn_mfma_f32_16x16x32_bf16(a1[ks], bfr, acc1[t], 0, 0, 0);
        }
    }

    float bmv[6], gv[6], bv[6];
#pragma unroll
    for (int t = 0; t < 6; ++t) {
        const int c = 16 * t + cl;
        bmv[t] = bm[c]; gv[t] = g[c]; bv[t] = be[c];
    }
    const int row0 = blockIdx.x * kBM2 + 16 * w + 4 * quad;
    ln_epilogue(acc0, bmv, gv, bv, out_msg, row0,       cl, kBE);
    ln_epilogue(acc1, bmv, gv, bv, out_msg, row0 + 128, cl, kBE);
}

// ---------------------------------------------------------------------------
// Scatter: decoupled segment-sum via pk-bf16 atomics. Thread = (edge, q):
// 24 threads cover one edge's 96 cols — one float4 read (coalesced, L3-hot)
// and TWO contiguous pk-atomics (sector-friendly, r5 lesson). Atomic count
// unchanged (15.36M = op-wall floor); loads, edge-idx reads, blocks halved.
// ---------------------------------------------------------------------------
__global__ __launch_bounds__(256) void scatter_pk(
    const float* __restrict__ out_msg, const int* __restrict__ edges,
    short* __restrict__ agg) {
    const int idx  = blockIdx.x * 256 + threadIdx.x;   // 30000 blocks exact
    const int edge = idx / 24;                         // magic-mul div
    const int q    = idx - edge * 24;
    const int b    = edge / kE;
    const int dn   = edges[(size_t)edge * 2 + 1];      // 24 threads share row
    const float4 v = reinterpret_cast<const float4*>(
        out_msg + (size_t)edge * kFil)[q];
    __hip_bfloat162 h0 = __float22bfloat162_rn(make_float2(v.x, v.y));
    __hip_bfloat162 h1 = __float22bfloat162_rn(make_float2(v.z, v.w));
    unsigned d0, d1;
    __builtin_memcpy(&d0, &h0, 4);
    __builtin_memcpy(&d1, &h1, 4);
    short* addr = agg + ((size_t)b * kN + dn) * kFil + 4 * q;
    asm volatile("global_atomic_pk_add_bf16 %0, %1, off"
                 :: "v"((unsigned long long)addr), "v"(d0) : "memory");
    asm volatile("global_atomic_pk_add_bf16 %0, %1, off"
                 :: "v"((unsigned long long)(addr + 2)), "v"(d1) : "memory");
}

// ---------------------------------------------------------------------------
// Update layer (MFMA): block = 128 nodes but only 4 WAVES (256 threads);
// each wave owns TWO 16-row tiles (r0, r0+64) sharing every B ds_read.
// Same grid (313) with half the waves/block -> 2x blocks/CU co-resident
// (upd was 1.2 blocks/CU at 8 waves; latency-bound — occupancy lever).
// agg is bf16 -> A-fragments for k>=64 are direct 16B loads (no convert).
// ---------------------------------------------------------------------------
__global__ __launch_bounds__(256) void upd_mfma(
    const float* __restrict__ nodes, const short* __restrict__ agg,
    const short* __restrict__ wuT, const float* __restrict__ bu,
    const float* __restrict__ g, const float* __restrict__ be,
    float* __restrict__ out_upd) {
    __shared__ short sB[96 * kLd];
    const int tid  = threadIdx.x;
    const int w    = tid >> 6;          // 0..3
    const int lane = tid & 63;
    const int cl   = lane & 15;
    const int quad = lane >> 4;

    const int r0 = blockIdx.x * kBM + 16 * w + cl;   // tile0 row
    const int r1 = r0 + 64;                          // tile1 row
    const int n0 = (r0 < kBN) ? r0 : (kBN - 1);      // clamp loads; store guarded
    const int n1 = (r1 < kBN) ? r1 : (kBN - 1);
    const float* np0 = nodes + (size_t)n0 * kF + 8 * quad;
    const float* np1 = nodes + (size_t)n1 * kF + 8 * quad;
    const short* ap0 = agg + (size_t)n0 * kFil;
    const short* ap1 = agg + (size_t)n1 * kFil;

    s16x8 a0[5], a1[5];
    a0[0] = loadA8(np0);       a1[0] = loadA8(np1);
    a0[1] = loadA8(np0 + 32);  a1[1] = loadA8(np1 + 32);
    a0[2] = *reinterpret_cast<const s16x8*>(ap0 + 8 * quad);
    a1[2] = *reinterpret_cast<const s16x8*>(ap1 + 8 * quad);
    a0[3] = *reinterpret_cast<const s16x8*>(ap0 + 32 + 8 * quad);
    a1[3] = *reinterpret_cast<const s16x8*>(ap1 + 32 + 8 * quad);
    a0[4] = *reinterpret_cast<const s16x8*>(ap0 + 64 + 8 * quad);
    a1[4] = *reinterpret_cast<const s16x8*>(ap1 + 64 + 8 * quad);

    for (int i = tid; i < 96 * kKp / 8; i += 256) {
        const int n = i / 20, c = i % 20;
        *reinterpret_cast<s16x8*>(sB + n * kLd + 8 * c) =
            *reinterpret_cast<const s16x8*>(wuT + n * kKp + 8 * c);
    }
    __syncthreads();

    f32x4 acc0[6] = {}, acc1[6] = {};
#pragma unroll
    for (int ks = 0; ks < 5; ++ks) {
#pragma unroll
        for (int t = 0; t < 6; ++t) {
            s16x8 bfr = *reinterpret_cast<const s16x8*>(
                sB + (16 * t + cl) * kLd + ks * 32 + quad * 8);
            acc0[t] = __builtin_amdgcn_mfma_f32_16x16x32_bf16(a0[ks], bfr, acc0[t], 0, 0, 0);
            acc1[t] = __builtin_amdgcn_mfma_f32_16x16x32_bf16(a1[ks], bfr, acc1[t], 0, 0, 0);
        }
    }

    float bmv[6], gv[6], bv[6];
#pragma unroll
    for (int t = 0; t < 6; ++t) {
        const int c = 16 * t + cl;
        bmv[t] = bu[c]; gv[t] = g[c]; bv[t] = be[c];
    }
    const int row0 = blockIdx.x * kBM + 16 * w + 4 * quad;
    ln_epilogue(acc0, bmv, gv, bv, out_upd, row0,      cl, kBN);
    ln_epilogue(acc1, bmv, gv, bv, out_upd, row0 + 64, cl, kBN);
}

extern "C" void kernel_launch(void* const* d_in, const int* in_sizes, int n_in,
                              void* d_out, int out_size, void* d_ws, size_t ws_size,
                              hipStream_t stream) {
    const float* nodes  = (const float*)d_in[0];
    const float* efeat  = (const float*)d_in[1];
    const int*   edges  = (const int*)d_in[2];
    const float* Wm     = (const float*)d_in[3];
    const float* bm     = (const float*)d_in[4];
    const float* ln_m_g = (const float*)d_in[5];
    const float* ln_m_b = (const float*)d_in[6];
    const float* Wu     = (const float*)d_in[7];
    const float* bu     = (const float*)d_in[8];
    const float* ln_u_g = (const float*)d_in[9];
    const float* ln_u_b = (const float*)d_in[10];

    float* out_upd = (float*)d_out;                           // (B,N,96) first
    float* out_msg = (float*)d_out + (size_t)kBN * kFil;      // (B,E,96) second

    // workspace layout; 16B-aligned segments
    short* wmT = (short*)d_ws;                                // 96*160 bf16
    short* wuT = wmT + 96 * kKp;                              // 96*160 bf16
    short* agg = wuT + 96 * kKp;                              // B*N*96 bf16 (7.7 MB)

    prep_wT<<<(96 * kKp + 255) / 256, 256, 0, stream>>>(Wm, Wu, wmT, wuT);

    msg_gemm<<<kBE / kBM2, 512, 0, stream>>>(
        nodes, efeat, edges, wmT, bm, ln_m_g, ln_m_b, out_msg, (s16x8*)agg);
    scatter_pk<<<kBE * 24 / 256, 256, 0, stream>>>(out_msg, edges, agg);
    upd_mfma<<<(kBN + kBM - 1) / kBM, 256, 0, stream>>>(
        nodes, agg, wuT, bu, ln_u_g, ln_u_b, out_upd);
}

// Round 11
// 268.785 us; speedup vs baseline: 1.1851x; 1.1851x over previous
//
#include <hip/hip_runtime.h>
#include <hip/hip_bf16.h>

typedef short s16x8 __attribute__((ext_vector_type(8)));
typedef float f32x4 __attribute__((ext_vector_type(4)));

namespace {
constexpr int kB   = 8;
constexpr int kN   = 5000;
constexpr int kE   = 40000;
constexpr int kF   = 64;
constexpr int kFE  = 16;
constexpr int kFil = 96;
constexpr float kEps = 1e-3f;
constexpr int kBN = kB * kN;   // 40000
constexpr int kBE = kB * kE;   // 320000
constexpr int kKp = 160;       // padded K (msg 144->160, upd exact 160)
constexpr int kLd = 168;       // LDS row stride in bf16 elems (r3-proven)
constexpr int kBM = 128;       // rows per block (upd)
constexpr int kBM2 = 256;      // rows per block (msg: 8 waves x 2 tiles)
constexpr int kZChunks = kBN * kFil / 8;          // 480000 16B agg chunks
constexpr int kZPerBlk = kZChunks / (kBE / kBM2); // 384 per msg block
}

// float -> bf16 (RNE) bit-twiddle — kept only for the tiny prep kernel
__device__ inline unsigned short f2bf(float x) {
    unsigned u = __float_as_uint(x);
    u += 0x7FFFu + ((u >> 16) & 1u);
    return (unsigned short)(u >> 16);
}

// 8x fp32 -> 8x bf16 via v_cvt_pk_bf16_f32 (RNE)
__device__ inline s16x8 pack8(const float4& a, const float4& b) {
    union { s16x8 s; __hip_bfloat162 h[4]; } r;
    r.h[0] = __float22bfloat162_rn(make_float2(a.x, a.y));
    r.h[1] = __float22bfloat162_rn(make_float2(a.z, a.w));
    r.h[2] = __float22bfloat162_rn(make_float2(b.x, b.y));
    r.h[3] = __float22bfloat162_rn(make_float2(b.z, b.w));
    return r.s;
}

// Load 8 consecutive fp32 (16B-aligned) -> bf16x8 A-fragment
__device__ inline s16x8 loadA8(const float* __restrict__ p) {
    const float4* q = reinterpret_cast<const float4*>(p);
    return pack8(q[0], q[1]);
}

// ---------------------------------------------------------------------------
// DPP cross-lane helpers (16-lane-row scope) — 1 VALU op per exchange,
// zero LDS traffic (r9-proven). quad_perm 0xB1 (xor1), 0x4E (xor2),
// row_ror:4 = 0x124, row_ror:8 = 0x128.
// ---------------------------------------------------------------------------
template <int CTRL>
__device__ inline float dpp_mov(float x) {
    return __int_as_float(__builtin_amdgcn_update_dpp(
        0, __float_as_int(x), CTRL, 0xF, 0xF, true));
}
__device__ inline float row16_sum(float s) {
    s += dpp_mov<0xB1>(s);    // + xor1
    s += dpp_mov<0x4E>(s);    // + xor2  -> quad sums
    s += dpp_mov<0x124>(s);   // + ror4
    s += dpp_mov<0x128>(s);   // + ror8  -> full 16-lane sum in every lane
    return s;
}

// ---------------------------------------------------------------------------
// Prep: W (K,96) fp32 -> WT (96,Kp) bf16, zero-padded K rows. 60 blocks.
// ---------------------------------------------------------------------------
__global__ __launch_bounds__(256) void prep_wT(
    const float* __restrict__ Wm, const float* __restrict__ Wu,
    short* __restrict__ wmT, short* __restrict__ wuT) {
    const int t = blockIdx.x * 256 + threadIdx.x;
    if (t >= 96 * kKp) return;
    const int n = t / kKp, k = t % kKp;
    wmT[t] = (k < 144) ? (short)f2bf(Wm[(size_t)k * 96 + n]) : (short)0;
    wuT[t] = (short)f2bf(Wu[(size_t)k * 96 + n]);
}

// ---------------------------------------------------------------------------
// bias/ReLU/LN epilogue + paired float2 store for one 16-row output tile
// group. acc layout: col=16t+cl, row=row0+j. All cross-lane via DPP.
// ---------------------------------------------------------------------------
__device__ inline void ln_epilogue(const f32x4 acc[6],
                                   const float bmv[6], const float gv[6],
                                   const float bv[6],
                                   float* __restrict__ out,
                                   int row0, int cl, int rowMax) {
#pragma unroll
    for (int j = 0; j < 4; ++j) {
        float v0[6];
        float s = 0.f;
#pragma unroll
        for (int t = 0; t < 6; ++t) {
            v0[t] = fmaxf(acc[t][j] + bmv[t], 0.f);
            s += v0[t];
        }
        s = row16_sum(s);
        const float mu = s * (1.f / 96.f);
        float q = 0.f;
#pragma unroll
        for (int t = 0; t < 6; ++t) {
            const float d = v0[t] - mu;
            q = fmaf(d, d, q);
        }
        q = row16_sum(q);
        const float inv = rsqrtf(q * (1.f / 96.f) + kEps);
        const int row = row0 + j;
        if (row < rowMax) {
            float* orow = out + (size_t)row * kFil;
            float ov[6];
#pragma unroll
            for (int t = 0; t < 6; ++t)
                ov[t] = (v0[t] - mu) * inv * gv[t] + bv[t];
#pragma unroll
            for (int t = 0; t < 6; ++t) {
                const float other = dpp_mov<0xB1>(ov[t]);   // partner col (xor1)
                if ((cl & 1) == 0) {
                    float2 st; st.x = ov[t]; st.y = other;
                    *reinterpret_cast<float2*>(orow + 16 * t + cl) = st;
                }
            }
        }
    }
}

// ---------------------------------------------------------------------------
// Message layer (MFMA): block = 256 edges, 8 waves; each wave owns TWO
// 16-row tiles (rA0, rA0+128) sharing every B-fragment ds_read. A-fragments
// loaded directly from global. Also zeroes its 6 KB agg slice (ordered
// before scatter by the kernel boundary; overlaps gather latency).
// ---------------------------------------------------------------------------
__global__ __launch_bounds__(512) void msg_gemm(
    const float* __restrict__ nodes, const float* __restrict__ efeat,
    const int* __restrict__ edges, const short* __restrict__ wmT,
    const float* __restrict__ bm, const float* __restrict__ g,
    const float* __restrict__ be, float* __restrict__ out_msg,
    s16x8* __restrict__ aggz) {
    __shared__ short sB[96 * kLd];    // 32256 B
    const int tid  = threadIdx.x;
    const int w    = tid >> 6;
    const int lane = tid & 63;
    const int cl   = lane & 15;
    const int quad = lane >> 4;

    const int rA0 = blockIdx.x * kBM2 + 16 * w + cl;   // 1250*256 = 320000 exact
    const int rA1 = rA0 + 128;
    const int b0  = rA0 / kE;
    const int b1  = rA1 / kE;
    const int2 e0 = reinterpret_cast<const int2*>(edges)[rA0];
    const int2 e1 = reinterpret_cast<const int2*>(edges)[rA1];
    const float* s0p = nodes + ((size_t)b0 * kN + e0.x) * kF + 8 * quad;
    const float* d0p = nodes + ((size_t)b0 * kN + e0.y) * kF + 8 * quad;
    const float* s1p = nodes + ((size_t)b1 * kN + e1.x) * kF + 8 * quad;
    const float* d1p = nodes + ((size_t)b1 * kN + e1.y) * kF + 8 * quad;

    s16x8 a0[5], a1[5];
    a0[0] = loadA8(s0p);       a1[0] = loadA8(s1p);
    a0[1] = loadA8(s0p + 32);  a1[1] = loadA8(s1p + 32);
    a0[2] = loadA8(d0p);       a1[2] = loadA8(d1p);
    a0[3] = loadA8(d0p + 32);  a1[3] = loadA8(d1p + 32);
    if (quad < 2) {
        a0[4] = loadA8(efeat + (size_t)rA0 * kFE + 8 * quad);
        a1[4] = loadA8(efeat + (size_t)rA1 * kFE + 8 * quad);
    } else {
        s16x8 z = {};
        a0[4] = z; a1[4] = z;          // zero-pad K 144..159
    }

    // zero this block's agg slice (384 16B chunks; threads 0..383)
    if (tid < kZPerBlk) {
        s16x8 z = {};
        aggz[(size_t)blockIdx.x * kZPerBlk + tid] = z;
    }

    for (int i = tid; i < 96 * kKp / 8; i += 512) {   // 1920 16B chunks
        const int n = i / 20, c = i % 20;
        *reinterpret_cast<s16x8*>(sB + n * kLd + 8 * c) =
            *reinterpret_cast<const s16x8*>(wmT + n * kKp + 8 * c);
    }
    __syncthreads();

    f32x4 acc0[6] = {}, acc1[6] = {};
#pragma unroll
    for (int ks = 0; ks < 5; ++ks) {
#pragma unroll
        for (int t = 0; t < 6; ++t) {
            s16x8 bfr = *reinterpret_cast<const s16x8*>(
                sB + (16 * t + cl) * kLd + ks * 32 + quad * 8);
            acc0[t] = __builtin_amdgcn_mfma_f32_16x16x32_bf16(a0[ks], bfr, acc0[t], 0, 0, 0);
            acc1[t] = __builtin_amdgcn_mfma_f32_16x16x32_bf16(a1[ks], bfr, acc1[t], 0, 0, 0);
        }
    }

    float bmv[6], gv[6], bv[6];
#pragma unroll
    for (int t = 0; t < 6; ++t) {
        const int c = 16 * t + cl;
        bmv[t] = bm[c]; gv[t] = g[c]; bv[t] = be[c];
    }
    const int row0 = blockIdx.x * kBM2 + 16 * w + 4 * quad;
    ln_epilogue(acc0, bmv, gv, bv, out_msg, row0,       cl, kBE);
    ln_epilogue(acc1, bmv, gv, bv, out_msg, row0 + 128, cl, kBE);
}

// ---------------------------------------------------------------------------
// Scatter: decoupled segment-sum via pk-bf16 atomics (r6/r9-proven optimum:
// 48 thr/edge, ONE atomic per thread, max TLP). Contiguous 192 B per edge
// (sector-friendly — r5 lesson); r10 proved 2-op/thread at half TLP is 27%
// worse at identical op count — keep the 1-op/max-wave shape.
// ---------------------------------------------------------------------------
__global__ __launch_bounds__(256) void scatter_pk(
    const float* __restrict__ out_msg, const int* __restrict__ edges,
    short* __restrict__ agg) {
    const int idx  = blockIdx.x * 256 + threadIdx.x;   // 60000 blocks exact
    const int edge = idx / 48;                         // magic-mul div
    const int pair = idx - edge * 48;
    const int b    = edge / kE;
    const int dn   = edges[(size_t)edge * 2 + 1];      // 48 threads share row
    const float2 v = reinterpret_cast<const float2*>(
        out_msg + (size_t)edge * kFil)[pair];
    __hip_bfloat162 hv = __float22bfloat162_rn(make_float2(v.x, v.y));
    unsigned dw;
    __builtin_memcpy(&dw, &hv, 4);
    short* addr = agg + ((size_t)b * kN + dn) * kFil + 2 * pair;
    asm volatile("global_atomic_pk_add_bf16 %0, %1, off"
                 :: "v"((unsigned long long)addr), "v"(dw) : "memory");
}

// ---------------------------------------------------------------------------
// Update layer (MFMA): block = 128 nodes, 8 waves (r9-proven; the 256-thread
// 2-tile variant regressed in r10 — reverted). X row = [node(64)|agg(96)].
// agg is bf16 -> A-fragments for k>=64 are direct 16B loads (no convert).
// ---------------------------------------------------------------------------
__global__ __launch_bounds__(512, 4) void upd_mfma(
    const float* __restrict__ nodes, const short* __restrict__ agg,
    const short* __restrict__ wuT, const float* __restrict__ bu,
    const float* __restrict__ g, const float* __restrict__ be,
    float* __restrict__ out_upd) {
    __shared__ short sB[96 * kLd];
    const int tid  = threadIdx.x;
    const int w    = tid >> 6;
    const int lane = tid & 63;
    const int cl   = lane & 15;
    const int quad = lane >> 4;

    const int node0 = blockIdx.x * kBM + 16 * w + cl;
    const int node  = (node0 < kBN) ? node0 : (kBN - 1);  // clamp loads; store guarded
    const float* np = nodes + (size_t)node * kF + 8 * quad;
    const short* ap = agg + (size_t)node * kFil;

    s16x8 a[5];
    a[0] = loadA8(np);                 // k =   0+8q+j -> node[ 0+8q..]
    a[1] = loadA8(np + 32);            // k =  32+8q+j -> node[32+8q..]
    a[2] = *reinterpret_cast<const s16x8*>(ap + 8 * quad);       // agg[ 0+8q..]
    a[3] = *reinterpret_cast<const s16x8*>(ap + 32 + 8 * quad);  // agg[32+8q..]
    a[4] = *reinterpret_cast<const s16x8*>(ap + 64 + 8 * quad);  // agg[64+8q..]

    for (int i = tid; i < 96 * kKp / 8; i += 512) {
        const int n = i / 20, c = i % 20;
        *reinterpret_cast<s16x8*>(sB + n * kLd + 8 * c) =
            *reinterpret_cast<const s16x8*>(wuT + n * kKp + 8 * c);
    }
    __syncthreads();

    f32x4 acc[6] = {};
#pragma unroll
    for (int ks = 0; ks < 5; ++ks) {
#pragma unroll
        for (int t = 0; t < 6; ++t) {
            s16x8 bfr = *reinterpret_cast<const s16x8*>(
                sB + (16 * t + cl) * kLd + ks * 32 + quad * 8);
            acc[t] = __builtin_amdgcn_mfma_f32_16x16x32_bf16(a[ks], bfr, acc[t], 0, 0, 0);
        }
    }

    float bmv[6], gv[6], bv[6];
#pragma unroll
    for (int t = 0; t < 6; ++t) {
        const int c = 16 * t + cl;
        bmv[t] = bu[c]; gv[t] = g[c]; bv[t] = be[c];
    }
    ln_epilogue(acc, bmv, gv, bv, out_upd,
                blockIdx.x * kBM + 16 * w + 4 * quad, cl, kBN);
}

extern "C" void kernel_launch(void* const* d_in, const int* in_sizes, int n_in,
                              void* d_out, int out_size, void* d_ws, size_t ws_size,
                              hipStream_t stream) {
    const float* nodes  = (const float*)d_in[0];
    const float* efeat  = (const float*)d_in[1];
    const int*   edges  = (const int*)d_in[2];
    const float* Wm     = (const float*)d_in[3];
    const float* bm     = (const float*)d_in[4];
    const float* ln_m_g = (const float*)d_in[5];
    const float* ln_m_b = (const float*)d_in[6];
    const float* Wu     = (const float*)d_in[7];
    const float* bu     = (const float*)d_in[8];
    const float* ln_u_g = (const float*)d_in[9];
    const float* ln_u_b = (const float*)d_in[10];

    float* out_upd = (float*)d_out;                           // (B,N,96) first
    float* out_msg = (float*)d_out + (size_t)kBN * kFil;      // (B,E,96) second

    // workspace layout; 16B-aligned segments
    short* wmT = (short*)d_ws;                                // 96*160 bf16
    short* wuT = wmT + 96 * kKp;                              // 96*160 bf16
    short* agg = wuT + 96 * kKp;                              // B*N*96 bf16 (7.7 MB)

    prep_wT<<<(96 * kKp + 255) / 256, 256, 0, stream>>>(Wm, Wu, wmT, wuT);

    msg_gemm<<<kBE / kBM2, 512, 0, stream>>>(
        nodes, efeat, edges, wmT, bm, ln_m_g, ln_m_b, out_msg, (s16x8*)agg);
    scatter_pk<<<kBE * 48 / 256, 256, 0, stream>>>(out_msg, edges, agg);
    upd_mfma<<<(kBN + kBM - 1) / kBM, 512, 0, stream>>>(
        nodes, agg, wuT, bu, ln_u_g, ln_u_b, out_upd);
}